// Round 5
// baseline (1693.141 us; speedup 1.0000x reference)
//
#include <hip/hip_runtime.h>
#include <math.h>

typedef unsigned short u16;
typedef unsigned int u32;
typedef __attribute__((ext_vector_type(8))) short short8;
typedef __attribute__((ext_vector_type(4))) float floatx4;

#define Hh 16
#define Mm 1024
#define Dd 512
#define Oo 512
#define Nn 16384
#define GRP 2   // heads per S/PV launch group

__device__ __forceinline__ u16 f2b(float f) {
    unsigned v = __float_as_uint(f);
    v += 0x7fffu + ((v >> 16) & 1u);
    return (u16)(v >> 16);
}
__device__ __forceinline__ short8 cvt8(const float* p) {
    float4 a = *(const float4*)p, b = *(const float4*)(p + 4);
    u16 o[8];
    o[0] = f2b(a.x); o[1] = f2b(a.y); o[2] = f2b(a.z); o[3] = f2b(a.w);
    o[4] = f2b(b.x); o[5] = f2b(b.y); o[6] = f2b(b.z); o[7] = f2b(b.w);
    return *(short8*)o;
}

// async global->LDS, 16B per lane; LDS dest = uniform base + lane*16
__device__ __forceinline__ void gl_lds16(const u16* g, u16* lds) {
    __builtin_amdgcn_global_load_lds(
        (const __attribute__((address_space(1))) u32*)g,
        (__attribute__((address_space(3))) u32*)lds, 16, 0, 0);
}

// ---------------------------------------------------------------------------
// Generic GEMM-BT (pre-stage, unchanged): C[h][m][n] = A[h][m][:] . B[h][n][:]
// ---------------------------------------------------------------------------
__global__ __launch_bounds__(256) void gemm_bt(
    const void* __restrict__ A, const void* __restrict__ B, const float* __restrict__ bias,
    void* __restrict__ C, int K, int lda, int ldb, int ldc,
    long sA, long sB, long sBias, long sC, int aF32, int bF32, int outBf)
{
    __shared__ u16 At[64][72];
    __shared__ u16 Bt[64][72];
    const int tid = threadIdx.x, lane = tid & 63, wid = tid >> 6;
    const int m0 = blockIdx.y * 64, n0 = blockIdx.x * 64;
    const int h = blockIdx.z;
    const int wm = wid >> 1, wn = wid & 1;
    const int rl = lane & 15, rq = (lane >> 4) * 4, gl8 = (lane >> 4) * 8;

    floatx4 zero4 = {0.f, 0.f, 0.f, 0.f};
    floatx4 acc[2][2];
    acc[0][0] = zero4; acc[0][1] = zero4; acc[1][0] = zero4; acc[1][1] = zero4;

    for (int k0 = 0; k0 < K; k0 += 64) {
#pragma unroll
        for (int i = 0; i < 2; i++) {
            int c = tid + i * 256;
            int r = c >> 3, cc = (c & 7) * 8;
            long aoff = (long)h * sA + (long)(m0 + r) * lda + k0 + cc;
            long boff = (long)h * sB + (long)(n0 + r) * ldb + k0 + cc;
            *(short8*)&At[r][cc] = aF32 ? cvt8((const float*)A + aoff)
                                        : *(const short8*)((const u16*)A + aoff);
            *(short8*)&Bt[r][cc] = bF32 ? cvt8((const float*)B + boff)
                                        : *(const short8*)((const u16*)B + boff);
        }
        __syncthreads();
#pragma unroll
        for (int ks = 0; ks < 2; ks++) {
            short8 a0 = *(const short8*)&At[wm * 32 + rl][ks * 32 + gl8];
            short8 a1 = *(const short8*)&At[wm * 32 + 16 + rl][ks * 32 + gl8];
            short8 b0 = *(const short8*)&Bt[wn * 32 + rl][ks * 32 + gl8];
            short8 b1 = *(const short8*)&Bt[wn * 32 + 16 + rl][ks * 32 + gl8];
            acc[0][0] = __builtin_amdgcn_mfma_f32_16x16x32_bf16(a0, b0, acc[0][0], 0, 0, 0);
            acc[0][1] = __builtin_amdgcn_mfma_f32_16x16x32_bf16(a0, b1, acc[0][1], 0, 0, 0);
            acc[1][0] = __builtin_amdgcn_mfma_f32_16x16x32_bf16(a1, b0, acc[1][0], 0, 0, 0);
            acc[1][1] = __builtin_amdgcn_mfma_f32_16x16x32_bf16(a1, b1, acc[1][1], 0, 0, 0);
        }
        __syncthreads();
    }

#pragma unroll
    for (int i = 0; i < 2; i++)
#pragma unroll
        for (int j = 0; j < 2; j++) {
            int col = n0 + wn * 32 + j * 16 + rl;
            float bb = bias ? bias[(long)h * sBias + col] : 0.f;
#pragma unroll
            for (int r = 0; r < 4; r++) {
                int row = m0 + wm * 32 + i * 16 + rq + r;
                long idx = (long)h * sC + (long)row * ldc + col;
                float v = acc[i][j][r] + bb;
                if (outBf) ((u16*)C)[idx] = f2b(v);
                else       ((float*)C)[idx] = v;
            }
        }
}

// ---------------------------------------------------------------------------
// Row softmax: rows of 512 fp32 logits -> bf16 probabilities. One wave/row.
// ---------------------------------------------------------------------------
__global__ __launch_bounds__(256) void softmax_rows(const float* __restrict__ L, u16* __restrict__ Kout)
{
    const int tid = threadIdx.x, lane = tid & 63, wid = tid >> 6;
    const long row = (long)blockIdx.x * 4 + wid;
    const float* p = L + row * 512 + lane * 8;
    float v[8];
    *(float4*)&v[0] = *(const float4*)p;
    *(float4*)&v[4] = *(const float4*)(p + 4);
    float mx = v[0];
#pragma unroll
    for (int i = 1; i < 8; i++) mx = fmaxf(mx, v[i]);
    for (int d = 1; d < 64; d <<= 1) mx = fmaxf(mx, __shfl_xor(mx, d));
    float s = 0.f;
#pragma unroll
    for (int i = 0; i < 8; i++) { v[i] = __expf(v[i] - mx); s += v[i]; }
    for (int d = 1; d < 64; d <<= 1) s += __shfl_xor(s, d);
    float inv = 1.f / s;
    u16 o[8];
#pragma unroll
    for (int i = 0; i < 8; i++) o[i] = f2b(v[i] * inv);
    *(short8*)(Kout + row * 512 + lane * 8) = *(short8*)o;
}

// ---------------------------------------------------------------------------
// kq fp32 -> bf16 converter; also zeroes the l accumulator (first 256 blocks)
// ---------------------------------------------------------------------------
__global__ __launch_bounds__(256) void cvt_zero(
    const float* __restrict__ in, u16* __restrict__ ob, float* __restrict__ lz)
{
    long i = ((long)blockIdx.x * 256 + threadIdx.x) * 8;
    *(short8*)(ob + i) = cvt8(in + i);
    if (blockIdx.x < 256) {
        long j = ((long)blockIdx.x * 256 + threadIdx.x) * 4;   // 256*256*4 = 262144 = Hh*Nn
        float4 z = {0.f, 0.f, 0.f, 0.f};
        *(float4*)(lz + j) = z;
    }
}

// ---------------------------------------------------------------------------
// S-GEMM (m97 structure): P[hg][m][n] = exp(kq[m] . key_h[n]), K=512.
// 128x128 tile, BK=64, 4 waves (2x2 quadrants), 4x4 acc/wave,
// global_load_lds width-16 staging, single LDS buffer, 2 barriers/K-step.
// Epilogue: exp -> bf16 P store + per-row sum atomics into l[h][row].
// ---------------------------------------------------------------------------
__global__ __launch_bounds__(256) void s_gemm(
    const u16* __restrict__ A,   // kqb [16384][512]
    const u16* __restrict__ B,   // keyb [16][1024][512]
    u16* __restrict__ P,         // [GRP][16384][1024]
    float* __restrict__ l,       // [16][16384]
    int h0)
{
    __shared__ u16 Asl[128 * 64];
    __shared__ u16 Bsl[128 * 64];
    const int tid = threadIdx.x, lane = tid & 63, wid = tid >> 6;
    const int n0 = blockIdx.x * 128, m0 = blockIdx.y * 128;
    const int hg = blockIdx.z, h = h0 + hg;
    const int wr = wid >> 1, wc = wid & 1;
    const int rl = lane & 15, rq = (lane >> 4) * 4, g8 = (lane >> 4) * 8;
    const int lrow = lane >> 3, lcol8 = (lane & 7) * 8;  // staging: 8 rows x 128B / instr
    const u16* Bh = B + (long)h * Mm * Dd;

    floatx4 zero4 = {0.f, 0.f, 0.f, 0.f};
    floatx4 acc[4][4];
#pragma unroll
    for (int i = 0; i < 4; i++)
#pragma unroll
        for (int j = 0; j < 4; j++) acc[i][j] = zero4;

    for (int k0 = 0; k0 < 512; k0 += 64) {
#pragma unroll
        for (int s = 0; s < 8; s++) {
            int t = wid * 8 + s;           // 0..15 -> A rows, 16..31 -> B rows
            int r0 = (t & 15) * 8;
            if (t < 16) gl_lds16(A  + (long)(m0 + r0 + lrow) * 512 + k0 + lcol8, &Asl[r0 * 64]);
            else        gl_lds16(Bh + (long)(n0 + r0 + lrow) * 512 + k0 + lcol8, &Bsl[r0 * 64]);
        }
        asm volatile("s_waitcnt vmcnt(0)" ::: "memory");
        __syncthreads();
#pragma unroll
        for (int ks = 0; ks < 2; ks++) {
            short8 af[4], bfr[4];
#pragma unroll
            for (int i = 0; i < 4; i++)
                af[i] = *(const short8*)&Asl[(wr * 64 + i * 16 + rl) * 64 + ks * 32 + g8];
#pragma unroll
            for (int j = 0; j < 4; j++)
                bfr[j] = *(const short8*)&Bsl[(wc * 64 + j * 16 + rl) * 64 + ks * 32 + g8];
#pragma unroll
            for (int i = 0; i < 4; i++)
#pragma unroll
                for (int j = 0; j < 4; j++)
                    acc[i][j] = __builtin_amdgcn_mfma_f32_16x16x32_bf16(af[i], bfr[j], acc[i][j], 0, 0, 0);
        }
        __syncthreads();
    }

    // epilogue: exp, store bf16 P, row-sum atomics into l
    u16* Pt = P + (long)hg * Nn * Mm;
    float rsum[4][4];
#pragma unroll
    for (int i = 0; i < 4; i++)
#pragma unroll
        for (int r = 0; r < 4; r++) rsum[i][r] = 0.f;
#pragma unroll
    for (int i = 0; i < 4; i++)
#pragma unroll
        for (int j = 0; j < 4; j++) {
            int col = n0 + wc * 64 + j * 16 + rl;
#pragma unroll
            for (int r = 0; r < 4; r++) {
                int row = m0 + wr * 64 + i * 16 + rq + r;
                float e = __expf(acc[i][j][r]);   // logits bounded (~|7|), no max-sub
                Pt[(long)row * Mm + col] = f2b(e);
                rsum[i][r] += e;
            }
        }
    for (int d = 1; d < 16; d <<= 1)
#pragma unroll
        for (int i = 0; i < 4; i++)
#pragma unroll
            for (int r = 0; r < 4; r++) rsum[i][r] += __shfl_xor(rsum[i][r], d);
    if (rl == 0)
#pragma unroll
        for (int i = 0; i < 4; i++)
#pragma unroll
            for (int r = 0; r < 4; r++)
                atomicAdd(&l[(long)h * Nn + m0 + wr * 64 + i * 16 + rq + r], rsum[i][r]);
}

// ---------------------------------------------------------------------------
// PV-GEMM (m97 structure): out[m][o] (+)= sum_hg (1/l_h[m]) * P[hg] @ vpt_h^T.
// Heads of the group looped inside; per-head acc scaled then folded, so out
// is touched once per launch. Epilogue adds bias (first group) or out.
// ---------------------------------------------------------------------------
__global__ __launch_bounds__(256) void pv_gemm(
    const u16* __restrict__ P,     // [GRP][16384][1024]
    const u16* __restrict__ V,     // vptb [16][512][1024]
    const float* __restrict__ l,   // [16][16384]
    const float* __restrict__ bfv,
    float* __restrict__ out,       // [16384][512]
    int h0, int first)
{
    __shared__ u16 Asl[128 * 64];
    __shared__ u16 Bsl[128 * 64];
    const int tid = threadIdx.x, lane = tid & 63, wid = tid >> 6;
    const int n0 = blockIdx.x * 128, m0 = blockIdx.y * 128;
    const int wr = wid >> 1, wc = wid & 1;
    const int rl = lane & 15, rq = (lane >> 4) * 4, g8 = (lane >> 4) * 8;
    const int lrow = lane >> 3, lcol8 = (lane & 7) * 8;

    floatx4 zero4 = {0.f, 0.f, 0.f, 0.f};
    floatx4 acc[4][4];
#pragma unroll
    for (int i = 0; i < 4; i++)
#pragma unroll
        for (int j = 0; j < 4; j++) acc[i][j] = zero4;

    for (int hg = 0; hg < GRP; hg++) {
        const int h = h0 + hg;
        const u16* Ah = P + (long)hg * Nn * Mm;
        const u16* Bh = V + (long)h * Oo * Mm;
        floatx4 a2[4][4];
#pragma unroll
        for (int i = 0; i < 4; i++)
#pragma unroll
            for (int j = 0; j < 4; j++) a2[i][j] = zero4;

        for (int k0 = 0; k0 < Mm; k0 += 64) {
#pragma unroll
            for (int s = 0; s < 8; s++) {
                int t = wid * 8 + s;
                int r0 = (t & 15) * 8;
                if (t < 16) gl_lds16(Ah + (long)(m0 + r0 + lrow) * Mm + k0 + lcol8, &Asl[r0 * 64]);
                else        gl_lds16(Bh + (long)(n0 + r0 + lrow) * Mm + k0 + lcol8, &Bsl[r0 * 64]);
            }
            asm volatile("s_waitcnt vmcnt(0)" ::: "memory");
            __syncthreads();
#pragma unroll
            for (int ks = 0; ks < 2; ks++) {
                short8 af[4], bfr[4];
#pragma unroll
                for (int i = 0; i < 4; i++)
                    af[i] = *(const short8*)&Asl[(wr * 64 + i * 16 + rl) * 64 + ks * 32 + g8];
#pragma unroll
                for (int j = 0; j < 4; j++)
                    bfr[j] = *(const short8*)&Bsl[(wc * 64 + j * 16 + rl) * 64 + ks * 32 + g8];
#pragma unroll
                for (int i = 0; i < 4; i++)
#pragma unroll
                    for (int j = 0; j < 4; j++)
                        a2[i][j] = __builtin_amdgcn_mfma_f32_16x16x32_bf16(af[i], bfr[j], a2[i][j], 0, 0, 0);
            }
            __syncthreads();
        }
        // fold per-head contribution scaled by 1/l
#pragma unroll
        for (int i = 0; i < 4; i++)
#pragma unroll
            for (int r = 0; r < 4; r++) {
                float inv = 1.f / l[(long)h * Nn + m0 + wr * 64 + i * 16 + rq + r];
#pragma unroll
                for (int j = 0; j < 4; j++) acc[i][j][r] += inv * a2[i][j][r];
            }
    }

    // epilogue: out = acc + bias (first group) or out += acc
#pragma unroll
    for (int i = 0; i < 4; i++)
#pragma unroll
        for (int j = 0; j < 4; j++) {
            int col = n0 + wc * 64 + j * 16 + rl;
#pragma unroll
            for (int r = 0; r < 4; r++) {
                int row = m0 + wr * 64 + i * 16 + rq + r;
                long idx = (long)row * Oo + col;
                float base = first ? bfv[col] : out[idx];
                out[idx] = base + acc[i][j][r];
            }
        }
}

// ---------------------------------------------------------------------------
extern "C" void kernel_launch(void* const* d_in, const int* in_sizes, int n_in,
                              void* d_out, int out_size, void* d_ws, size_t ws_size,
                              hipStream_t stream)
{
    const float* k    = (const float*)d_in[0];   // [N][O] fp32
    const void*  mems = d_in[1];                 // [H][M][D] fp32
    const void*  Wk   = d_in[2];                 // [H][O][D] fp32
    const float* bk   = (const float*)d_in[3];   // [H][O] fp32
    const void*  Wv   = d_in[4];                 // [H][O][D] fp32
    const float* bv   = (const float*)d_in[5];   // [H][O] fp32
    const void*  Wf   = d_in[6];                 // [O][H*O] fp32
    const float* bfv  = (const float*)d_in[7];   // [O] fp32
    float* out = (float*)d_out;

    // workspace layout (peak 113 MB):
    //   [0,16M)    keyb  bf16 [16][1024][512]
    //   [16,32M)   vptb  bf16 [16][512][1024]
    //   [32,48M)   kqb   bf16 [16384][512]
    //   [48,49M)   l     fp32 [16][16384]
    //   [49,113M)  Pbuf  bf16 [GRP][16384][1024]  (reused per group)
    //     transient aliases inside Pbuf (dead before first s_gemm):
    //     logits fp32 32MB @ +0, valb bf16 16MB @ +32M
    char* ws = (char*)d_ws;
    u16*   keyb   = (u16*)ws;
    u16*   vptb   = (u16*)(ws + (size_t)Hh * Mm * Oo * 2);
    u16*   kqb    = (u16*)(ws + (size_t)Hh * Mm * Oo * 4);
    float* lbuf   = (float*)(ws + (size_t)Hh * Mm * Oo * 4 + (size_t)Nn * Dd * 2);
    char*  pbase  = ws + (size_t)Hh * Mm * Oo * 4 + (size_t)Nn * Dd * 2 + (size_t)Hh * Nn * 4;
    u16*   Pbuf   = (u16*)pbase;
    float* logits = (float*)pbase;                       // transient
    u16*   valb   = (u16*)(pbase + (size_t)Hh * Mm * Oo * 4);  // transient

    // key logits: [h][m][o] = mems_h @ Wk_h^T + bk_h   (fp32 out)
    gemm_bt<<<dim3(8, 16, 16), 256, 0, stream>>>(
        mems, Wk, bk, logits, 512, 512, 512, 512,
        (long)Mm * Dd, (long)Oo * Dd, 512L, (long)Mm * Oo, 1, 1, 0);

    // mem_key = softmax(logits) -> bf16
    softmax_rows<<<dim3(Hh * Mm / 4), 256, 0, stream>>>(logits, keyb);

    // val: [h][m][o] = mems_h @ Wv_h^T + bv_h   (bf16 out)
    gemm_bt<<<dim3(8, 16, 16), 256, 0, stream>>>(
        mems, Wv, bv, valb, 512, 512, 512, 512,
        (long)Mm * Dd, (long)Oo * Dd, 512L, (long)Mm * Oo, 1, 1, 1);

    // V'^T: [h][o][m] = Wf[:, h*O:(h+1)*O] @ val_h^T   (bf16 out, transposed)
    gemm_bt<<<dim3(16, 8, 16), 256, 0, stream>>>(
        Wf, valb, nullptr, vptb, 512, Hh * Oo, 512, 1024,
        512L, (long)Mm * Oo, 0L, (long)Oo * Mm, 1, 0, 1);

    // kq -> bf16, and zero l
    cvt_zero<<<dim3(Nn * Dd / (256 * 8)), 256, 0, stream>>>(k, kqb, lbuf);

    // attention as per-group GEMM pairs
    for (int g = 0; g < Hh / GRP; g++) {
        s_gemm<<<dim3(Mm / 128, Nn / 128, GRP), 256, 0, stream>>>(
            kqb, keyb, Pbuf, lbuf, g * GRP);
        pv_gemm<<<dim3(Oo / 128, Nn / 128, 1), 256, 0, stream>>>(
            Pbuf, vptb, lbuf, bfv, out, g * GRP, g == 0);
    }
}